// Round 3
// baseline (352.441 us; speedup 1.0000x reference)
//
#include <hip/hip_runtime.h>
#include <hip/hip_bf16.h>
#include <math.h>

// Problem constants (B=2,S=2048 -> T=4096 tokens)
#define T_TOKENS 4096
#define D_DIM 768
#define F_DIM 3072
#define E_NUM 8

#define BM 128
#define BN 128
#define BK 32
#define RBMAX 72          // max padded row-blocks: (8192 + 8*127)/128 <= 72
#define KS_DOWN 4
#define KCH (F_DIM / KS_DOWN)   // 768 per down-GEMM K-chunk
#define NBU (F_DIM / BN)        // 24
#define NBD (D_DIM / BN)        // 6

typedef __attribute__((ext_vector_type(8))) short short8;
typedef __attribute__((ext_vector_type(4))) float float4v;
typedef unsigned short ushort_t;

__device__ __forceinline__ ushort_t f2bf(float f) {
    union { float f; unsigned u; } v; v.f = f;
    unsigned r = v.u + 0x7fffu + ((v.u >> 16) & 1u);   // RNE
    return (ushort_t)(r >> 16);
}

__device__ __forceinline__ float gelu_fast(float v) {
    float u = v + 0.044715f * v * v * v;
    return v / (1.f + __expf(-1.5957691216f * u));
}

#define GLOAD_LDS16(gp, lp) __builtin_amdgcn_global_load_lds( \
    (const __attribute__((address_space(1))) void*)(gp),      \
    (__attribute__((address_space(3))) void*)(lp), 16, 0, 0)

// ============================================================ fused prep
// regions: [0,4608) wup transpose | [4608,9216) wdn transpose |
//          [9216,10240) gate      | [10240,11264) x->bf16     | [11264,11776) zero out
#define PB_WUP 4608
#define PB_WDN 4608
#define PB_GATE 1024
#define PB_CVT 1024
#define PB_ZERO 512
#define PB_TOTAL (PB_WUP + PB_WDN + PB_GATE + PB_CVT + PB_ZERO)

__global__ void k_prep(const float* __restrict__ x, const float* __restrict__ gw,
                       const float* __restrict__ wup, const float* __restrict__ wdn,
                       int* __restrict__ counts, int* __restrict__ list,
                       float* __restrict__ wtmp, ushort_t* __restrict__ xb,
                       ushort_t* __restrict__ wupT, ushort_t* __restrict__ wdnT,
                       float* __restrict__ out) {
    __shared__ float tile[64][65];
    int bid = blockIdx.x;

    if (bid < PB_WUP + PB_WDN) {
        // transpose+convert: in [E][R][C] fp32 -> out [E][C][R] bf16
        const float* in; ushort_t* op; int R, C, lb;
        if (bid < PB_WUP) { in = wup; op = wupT; R = D_DIM; C = F_DIM; lb = bid; }
        else              { in = wdn; op = wdnT; R = F_DIM; C = D_DIM; lb = bid - PB_WUP; }
        int tpr = C / 64, tpc = R / 64;
        int e = lb / (tpr * tpc);
        int rem = lb % (tpr * tpc);
        int r0 = (rem / tpr) * 64, c0 = (rem % tpr) * 64;
        const float* ip = in + (size_t)e * R * C;
        ushort_t* opp = op + (size_t)e * R * C;
        int tr = threadIdx.x >> 6, tc = threadIdx.x & 63;
#pragma unroll
        for (int i = 0; i < 16; ++i) {
            int r = tr + i * 4;
            tile[r][tc] = ip[(size_t)(r0 + r) * C + c0 + tc];
        }
        __syncthreads();
#pragma unroll
        for (int i = 0; i < 16; ++i) {
            int rr = tr + i * 4;
            opp[(size_t)(c0 + rr) * R + r0 + tc] = f2bf(tile[tc][rr]);
        }
        return;
    }
    bid -= PB_WUP + PB_WDN;

    if (bid < PB_GATE) {
        int wave = threadIdx.x >> 6, lane = threadIdx.x & 63;
        int t = bid * 4 + wave;
        float acc[E_NUM];
#pragma unroll
        for (int e = 0; e < E_NUM; ++e) acc[e] = 0.f;
        const float* xr = x + (size_t)t * D_DIM;
        for (int d = lane; d < D_DIM; d += 64) {
            float xv = xr[d];
            const float* g = gw + d * E_NUM;
#pragma unroll
            for (int e = 0; e < E_NUM; ++e) acc[e] += xv * g[e];
        }
#pragma unroll
        for (int e = 0; e < E_NUM; ++e) {
#pragma unroll
            for (int s = 32; s >= 1; s >>= 1) acc[e] += __shfl_xor(acc[e], s);
        }
        if (lane == 0) {
            float mx = acc[0];
#pragma unroll
            for (int e = 1; e < E_NUM; ++e) mx = fmaxf(mx, acc[e]);
            float p[E_NUM], sum = 0.f;
#pragma unroll
            for (int e = 0; e < E_NUM; ++e) { p[e] = expf(acc[e] - mx); sum += p[e]; }
            float inv = 1.f / sum;
#pragma unroll
            for (int e = 0; e < E_NUM; ++e) p[e] *= inv;
            int e1 = 0;
#pragma unroll
            for (int e = 1; e < E_NUM; ++e) if (p[e] > p[e1]) e1 = e;
            int e2 = (e1 == 0) ? 1 : 0;
#pragma unroll
            for (int e = 0; e < E_NUM; ++e) if (e != e1 && p[e] > p[e2]) e2 = e;
            int s1 = atomicAdd(&counts[e1], 1);
            list[e1 * T_TOKENS + s1] = t;  wtmp[e1 * T_TOKENS + s1] = p[e1];
            int s2 = atomicAdd(&counts[e2], 1);
            list[e2 * T_TOKENS + s2] = t;  wtmp[e2 * T_TOKENS + s2] = p[e2];
        }
        return;
    }
    bid -= PB_GATE;

    if (bid < PB_CVT) {
        int n4 = T_TOKENS * D_DIM / 4;
        for (int j = bid * 256 + threadIdx.x; j < n4; j += PB_CVT * 256) {
            float4v v = ((const float4v*)x)[j];
            unsigned long long o =
                (unsigned long long)f2bf(v[0]) |
                ((unsigned long long)f2bf(v[1]) << 16) |
                ((unsigned long long)f2bf(v[2]) << 32) |
                ((unsigned long long)f2bf(v[3]) << 48);
            ((unsigned long long*)xb)[j] = o;
        }
        return;
    }
    bid -= PB_CVT;

    {   // zero out
        int n4 = T_TOKENS * D_DIM / 4;
        float4v z = {0.f, 0.f, 0.f, 0.f};
        for (int j = bid * 256 + threadIdx.x; j < n4; j += PB_ZERO * 256)
            ((float4v*)out)[j] = z;
    }
}

// ---------------------------------------------------------------- finalize
__global__ void k_finalize(const int* __restrict__ counts, int* __restrict__ pcount,
                           int* __restrict__ offs, int* __restrict__ nrb,
                           int* __restrict__ rbmap) {
    if (threadIdx.x == 0) {
        int acc = 0, rb = 0;
        for (int e = 0; e < E_NUM; ++e) {
            int pc = (counts[e] + BM - 1) / BM * BM;
            pcount[e] = pc;
            offs[e] = acc;
            for (int i = 0; i < pc / BM; ++i) rbmap[rb++] = e;
            acc += pc;
        }
        nrb[0] = rb;
    }
}

// ---------------------------------------------------------------- compact
__global__ void k_compact(const int* __restrict__ counts, const int* __restrict__ pcount,
                          const int* __restrict__ offs, const int* __restrict__ list,
                          const float* __restrict__ wtmp, int* __restrict__ clist,
                          float* __restrict__ cw) {
    int e = blockIdx.y;
    int s = blockIdx.x * 256 + threadIdx.x;
    if (s >= pcount[e]) return;
    int g = offs[e] + s;
    if (s < counts[e]) {
        clist[g] = list[e * T_TOKENS + s];
        cw[g] = wtmp[e * T_TOKENS + s];
    } else {
        clist[g] = 0;
        cw[g] = 0.f;
    }
}

// ---------------------------------------------------------------- up GEMM
// flat grid 1728, XCD-chunk swizzle, rb-inner (B panel read once device-wide)
__global__ void k_up_gemm(const ushort_t* __restrict__ xb, const ushort_t* __restrict__ wupT,
                          const float* __restrict__ b_up, const int* __restrict__ nrb,
                          const int* __restrict__ rbmap, const int* __restrict__ clist,
                          ushort_t* __restrict__ h) {
    int wg = blockIdx.x;
    int lin = (wg & 7) * (NBU * RBMAX / 8) + (wg >> 3);
    int nb = lin / RBMAX;
    int rb = lin % RBMAX;
    if (rb >= nrb[0]) return;
    int e = rbmap[rb];
    __shared__ __align__(16) ushort_t As[2][BM][BK];
    __shared__ __align__(16) ushort_t Bs[2][BN][BK];
    int t = threadIdx.x, wave = t >> 6, lane = t & 63;
    int wm = wave >> 1, wn = wave & 1;

    int row0 = rb * BM;
    int tokA0 = clist[row0 + (t >> 2)];
    int tokA1 = clist[row0 + 64 + (t >> 2)];
    const ushort_t* wb = wupT + (size_t)e * F_DIM * D_DIM + (size_t)(nb * BN) * D_DIM;

    float4v acc[4][4];
#pragma unroll
    for (int i = 0; i < 4; ++i)
#pragma unroll
        for (int j = 0; j < 4; ++j)
#pragma unroll
            for (int q = 0; q < 4; ++q) acc[i][j][q] = 0.f;

    int csw = (((t & 3) ^ ((t >> 3) & 3))) * 8;    // staged src chunk (swizzled)
    int swoff = (((lane >> 4) ^ (((lane & 15) >> 1) & 3))) * 8;  // read-side

    const ushort_t* gA0 = xb + (size_t)tokA0 * D_DIM + csw;
    const ushort_t* gA1 = xb + (size_t)tokA1 * D_DIM + csw;
    const ushort_t* gB0 = wb + (size_t)(t >> 2) * D_DIM + csw;
    const ushort_t* gB1 = wb + (size_t)(64 + (t >> 2)) * D_DIM + csw;

#define STAGE_UP(buf, kt) do { int k0 = (kt) * BK;                       \
        char* AsB = (char*)&As[buf][0][0]; char* BsB = (char*)&Bs[buf][0][0]; \
        GLOAD_LDS16(gA0 + k0, AsB + wave * 1024);                        \
        GLOAD_LDS16(gA1 + k0, AsB + 4096 + wave * 1024);                 \
        GLOAD_LDS16(gB0 + k0, BsB + wave * 1024);                        \
        GLOAD_LDS16(gB1 + k0, BsB + 4096 + wave * 1024); } while (0)

    STAGE_UP(0, 0);
    __syncthreads();
    const int nt = D_DIM / BK;
    for (int kt = 0; kt < nt; ++kt) {
        int buf = kt & 1;
        if (kt + 1 < nt) STAGE_UP(buf ^ 1, kt + 1);
        short8 af[4], bfr[4];
#pragma unroll
        for (int m = 0; m < 4; ++m)
            af[m] = *(const short8*)&As[buf][wm * 64 + m * 16 + (lane & 15)][swoff];
#pragma unroll
        for (int n = 0; n < 4; ++n)
            bfr[n] = *(const short8*)&Bs[buf][wn * 64 + n * 16 + (lane & 15)][swoff];
#pragma unroll
        for (int m = 0; m < 4; ++m)
#pragma unroll
            for (int n = 0; n < 4; ++n)
                acc[m][n] = __builtin_amdgcn_mfma_f32_16x16x32_bf16(af[m], bfr[n], acc[m][n], 0, 0, 0);
        __syncthreads();
    }

#pragma unroll
    for (int m = 0; m < 4; ++m) {
        int row_local = wm * 64 + m * 16 + (lane >> 4) * 4;
#pragma unroll
        for (int n = 0; n < 4; ++n) {
            int col = nb * BN + wn * 64 + n * 16 + (lane & 15);
            float bia = b_up[e * F_DIM + col];
#pragma unroll
            for (int j = 0; j < 4; ++j) {
                float v = acc[m][n][j] + bia;
                h[(size_t)(row0 + row_local + j) * F_DIM + col] = f2bf(gelu_fast(v));
            }
        }
    }
}

// ---------------------------------------------------------------- down GEMM + combine
// flat grid 1728, XCD-chunk swizzle, nb-inner (B panel set L2-resident per XCD)
__global__ void k_down_gemm(const ushort_t* __restrict__ h, const ushort_t* __restrict__ wdT,
                            const float* __restrict__ b_down, const int* __restrict__ nrb,
                            const int* __restrict__ rbmap, const int* __restrict__ clist,
                            const float* __restrict__ cw, float* __restrict__ out) {
    int wg = blockIdx.x;
    int lin = (wg & 7) * (NBD * RBMAX * KS_DOWN / 8) + (wg >> 3);
    int nb = lin % NBD;
    int rest = lin / NBD;
    int rb = rest % RBMAX;
    int kc = rest / RBMAX;
    if (rb >= nrb[0]) return;
    int e = rbmap[rb];
    __shared__ __align__(16) ushort_t As[2][BM][BK];
    __shared__ __align__(16) ushort_t Bs[2][BN][BK];
    int t = threadIdx.x, wave = t >> 6, lane = t & 63;
    int wm = wave >> 1, wn = wave & 1;

    int row0 = rb * BM;
    int kbase = kc * KCH;
    const ushort_t* ha = h + (size_t)row0 * F_DIM + kbase;
    const ushort_t* wb = wdT + (size_t)e * D_DIM * F_DIM + (size_t)(nb * BN) * F_DIM + kbase;

    float4v acc[4][4];
#pragma unroll
    for (int i = 0; i < 4; ++i)
#pragma unroll
        for (int j = 0; j < 4; ++j)
#pragma unroll
            for (int q = 0; q < 4; ++q) acc[i][j][q] = 0.f;

    int csw = (((t & 3) ^ ((t >> 3) & 3))) * 8;
    int swoff = (((lane >> 4) ^ (((lane & 15) >> 1) & 3))) * 8;

    const ushort_t* gA0 = ha + (size_t)(t >> 2) * F_DIM + csw;
    const ushort_t* gA1 = ha + (size_t)(64 + (t >> 2)) * F_DIM + csw;
    const ushort_t* gB0 = wb + (size_t)(t >> 2) * F_DIM + csw;
    const ushort_t* gB1 = wb + (size_t)(64 + (t >> 2)) * F_DIM + csw;

#define STAGE_DN(buf, kt) do { int k0 = (kt) * BK;                       \
        char* AsB = (char*)&As[buf][0][0]; char* BsB = (char*)&Bs[buf][0][0]; \
        GLOAD_LDS16(gA0 + k0, AsB + wave * 1024);                        \
        GLOAD_LDS16(gA1 + k0, AsB + 4096 + wave * 1024);                 \
        GLOAD_LDS16(gB0 + k0, BsB + wave * 1024);                        \
        GLOAD_LDS16(gB1 + k0, BsB + 4096 + wave * 1024); } while (0)

    STAGE_DN(0, 0);
    __syncthreads();
    const int nt = KCH / BK;
    for (int kt = 0; kt < nt; ++kt) {
        int buf = kt & 1;
        if (kt + 1 < nt) STAGE_DN(buf ^ 1, kt + 1);
        short8 af[4], bfr[4];
#pragma unroll
        for (int m = 0; m < 4; ++m)
            af[m] = *(const short8*)&As[buf][wm * 64 + m * 16 + (lane & 15)][swoff];
#pragma unroll
        for (int n = 0; n < 4; ++n)
            bfr[n] = *(const short8*)&Bs[buf][wn * 64 + n * 16 + (lane & 15)][swoff];
#pragma unroll
        for (int m = 0; m < 4; ++m)
#pragma unroll
            for (int n = 0; n < 4; ++n)
                acc[m][n] = __builtin_amdgcn_mfma_f32_16x16x32_bf16(af[m], bfr[n], acc[m][n], 0, 0, 0);
        __syncthreads();
    }

#pragma unroll
    for (int m = 0; m < 4; ++m) {
        int row_local = wm * 64 + m * 16 + (lane >> 4) * 4;
#pragma unroll
        for (int j = 0; j < 4; ++j) {
            int rl = row0 + row_local + j;
            int tok = clist[rl];
            float w = cw[rl];
            if (w != 0.f) {
#pragma unroll
                for (int n = 0; n < 4; ++n) {
                    int col = nb * BN + wn * 64 + n * 16 + (lane & 15);
                    float v = acc[m][n][j];
                    if (kc == 0) v += b_down[e * D_DIM + col];
                    atomicAdd(&out[(size_t)tok * D_DIM + col], w * v);
                }
            }
        }
    }
}

// ---------------------------------------------------------------- launch
extern "C" void kernel_launch(void* const* d_in, const int* in_sizes, int n_in,
                              void* d_out, int out_size, void* d_ws, size_t ws_size,
                              hipStream_t stream) {
    const float* x   = (const float*)d_in[0];   // [2,2048,768]
    const float* gw  = (const float*)d_in[1];   // [768,8]
    const float* wup = (const float*)d_in[2];   // [8,768,3072]
    const float* bup = (const float*)d_in[3];   // [8,3072]
    const float* wdn = (const float*)d_in[4];   // [8,3072,768]
    const float* bdn = (const float*)d_in[5];   // [8,768]
    float* out = (float*)d_out;

    char* ws = (char*)d_ws;
    int*   counts = (int*)(ws);
    int*   pcount = (int*)(ws + 32);
    int*   offs   = (int*)(ws + 64);
    int*   nrb    = (int*)(ws + 96);
    int*   rbmap  = (int*)(ws + 128);
    int*   list   = (int*)(ws + 1024);
    float* wtmp   = (float*)(ws + 1024 + (size_t)E_NUM * T_TOKENS * 4);
    size_t p = 1024 + (size_t)E_NUM * T_TOKENS * 8;
    int*   clist  = (int*)(ws + p); p += (size_t)(RBMAX * BM) * 4;
    float* cwp    = (float*)(ws + p); p += (size_t)(RBMAX * BM) * 4;
    p = (p + 255) & ~(size_t)255;
    ushort_t* xb   = (ushort_t*)(ws + p); p += (size_t)T_TOKENS * D_DIM * 2;
    ushort_t* wupT = (ushort_t*)(ws + p); p += (size_t)E_NUM * D_DIM * F_DIM * 2;
    ushort_t* wdnT = (ushort_t*)(ws + p); p += (size_t)E_NUM * D_DIM * F_DIM * 2;
    ushort_t* hbuf = (ushort_t*)(ws + p); p += (size_t)(RBMAX * BM) * F_DIM * 2;

    hipMemsetAsync(counts, 0, E_NUM * sizeof(int), stream);
    k_prep<<<PB_TOTAL, 256, 0, stream>>>(x, gw, wup, wdn, counts, list, wtmp,
                                         xb, wupT, wdnT, out);
    k_finalize<<<1, 64, 0, stream>>>(counts, pcount, offs, nrb, rbmap);
    k_compact<<<dim3(T_TOKENS / 256, E_NUM), 256, 0, stream>>>(
        counts, pcount, offs, list, wtmp, clist, cwp);
    k_up_gemm<<<NBU * RBMAX, 256, 0, stream>>>(
        xb, wupT, bup, nrb, rbmap, clist, hbuf);
    k_down_gemm<<<NBD * RBMAX * KS_DOWN, 256, 0, stream>>>(
        hbuf, wdnT, bdn, nrb, rbmap, clist, cwp, out);
}

// Round 4
// 348.958 us; speedup vs baseline: 1.0100x; 1.0100x over previous
//
#include <hip/hip_runtime.h>
#include <hip/hip_bf16.h>
#include <math.h>

// Problem constants (B=2,S=2048 -> T=4096 tokens)
#define T_TOKENS 4096
#define D_DIM 768
#define F_DIM 3072
#define E_NUM 8

#define BM 128
#define BN 128
#define BK 32
#define RBMAX 72          // max padded row-blocks: (8192 + 8*127)/128 <= 72
#define KS_DOWN 4
#define KCH (F_DIM / KS_DOWN)   // 768 per down-GEMM K-chunk
#define NBU (F_DIM / BN)        // 24
#define NBD (D_DIM / BN)        // 6
#define UP_BLOCKS (NBU * RBMAX) // 1728

typedef __attribute__((ext_vector_type(8))) short short8;
typedef __attribute__((ext_vector_type(4))) short short4v;
typedef __attribute__((ext_vector_type(4))) float float4v;
typedef unsigned short ushort_t;

__device__ __forceinline__ ushort_t f2bf(float f) {
    union { float f; unsigned u; } v; v.f = f;
    unsigned r = v.u + 0x7fffu + ((v.u >> 16) & 1u);   // RNE
    return (ushort_t)(r >> 16);
}

__device__ __forceinline__ float gelu_fast(float v) {
    float u = v + 0.044715f * v * v * v;
    return v / (1.f + __expf(-1.5957691216f * u));
}

#define GLOAD_LDS16(gp, lp) __builtin_amdgcn_global_load_lds( \
    (const __attribute__((address_space(1))) void*)(gp),      \
    (__attribute__((address_space(3))) void*)(lp), 16, 0, 0)

// ------------------------------------------------- vectorized transpose tile
// one 64x64 tile: in [E][R][C] fp32 -> out [E][C][R] bf16
// float4 loads, fp32 LDS tile, short4 stores
__device__ __forceinline__ void transpose_tile64(const float* __restrict__ in,
                                                 ushort_t* __restrict__ outp,
                                                 int R, int C, int lb,
                                                 float (*tile)[65]) {
    int tpr = C / 64, tpc = R / 64;
    int e = lb / (tpr * tpc);
    int rem = lb % (tpr * tpc);
    int r0 = (rem / tpr) * 64, c0 = (rem % tpr) * 64;
    const float* ip = in + (size_t)e * R * C;
    ushort_t* opp = outp + (size_t)e * R * C;
    int tr = threadIdx.x >> 4;           // 0..15
    int tc = (threadIdx.x & 15) * 4;     // 0,4,...,60
#pragma unroll
    for (int i = 0; i < 4; ++i) {
        int r = tr + i * 16;
        *(float4v*)&tile[r][tc] = *(const float4v*)&ip[(size_t)(r0 + r) * C + c0 + tc];
    }
    __syncthreads();
#pragma unroll
    for (int i = 0; i < 4; ++i) {
        int rr = tr + i * 16;            // output row (= original col c0+rr)
        short4v sv;
#pragma unroll
        for (int k = 0; k < 4; ++k) sv[k] = (short)f2bf(tile[tc + k][rr]);
        *(short4v*)&opp[(size_t)(c0 + rr) * R + r0 + tc] = sv;
    }
}

// ============================================================ prep phase 1
// regions: [0,4608) wup transpose | [4608,5632) gate |
//          [5632,6656) x->bf16    | [6656,7168) zero out
#define TB_WUP 4608
#define PB_GATE 1024
#define PB_CVT 1024
#define PB_ZERO 512
#define P1_TOTAL (TB_WUP + PB_GATE + PB_CVT + PB_ZERO)

__global__ void k_prep1(const float* __restrict__ x, const float* __restrict__ gw,
                        const float* __restrict__ wup,
                        int* __restrict__ counts, int* __restrict__ list,
                        float* __restrict__ wtmp, ushort_t* __restrict__ xb,
                        ushort_t* __restrict__ wupT, float* __restrict__ out) {
    __shared__ float tile[64][65];
    int bid = blockIdx.x;

    if (bid < TB_WUP) {
        transpose_tile64(wup, wupT, D_DIM, F_DIM, bid, tile);
        return;
    }
    bid -= TB_WUP;

    if (bid < PB_GATE) {
        int wave = threadIdx.x >> 6, lane = threadIdx.x & 63;
        int t = bid * 4 + wave;
        float acc[E_NUM];
#pragma unroll
        for (int e = 0; e < E_NUM; ++e) acc[e] = 0.f;
        const float* xr = x + (size_t)t * D_DIM;
        for (int d = lane; d < D_DIM; d += 64) {
            float xv = xr[d];
            const float* g = gw + d * E_NUM;
#pragma unroll
            for (int e = 0; e < E_NUM; ++e) acc[e] += xv * g[e];
        }
#pragma unroll
        for (int e = 0; e < E_NUM; ++e) {
#pragma unroll
            for (int s = 32; s >= 1; s >>= 1) acc[e] += __shfl_xor(acc[e], s);
        }
        if (lane == 0) {
            float mx = acc[0];
#pragma unroll
            for (int e = 1; e < E_NUM; ++e) mx = fmaxf(mx, acc[e]);
            float p[E_NUM], sum = 0.f;
#pragma unroll
            for (int e = 0; e < E_NUM; ++e) { p[e] = expf(acc[e] - mx); sum += p[e]; }
            float inv = 1.f / sum;
#pragma unroll
            for (int e = 0; e < E_NUM; ++e) p[e] *= inv;
            int e1 = 0;
#pragma unroll
            for (int e = 1; e < E_NUM; ++e) if (p[e] > p[e1]) e1 = e;
            int e2 = (e1 == 0) ? 1 : 0;
#pragma unroll
            for (int e = 0; e < E_NUM; ++e) if (e != e1 && p[e] > p[e2]) e2 = e;
            int s1 = atomicAdd(&counts[e1], 1);
            list[e1 * T_TOKENS + s1] = t;  wtmp[e1 * T_TOKENS + s1] = p[e1];
            int s2 = atomicAdd(&counts[e2], 1);
            list[e2 * T_TOKENS + s2] = t;  wtmp[e2 * T_TOKENS + s2] = p[e2];
        }
        return;
    }
    bid -= PB_GATE;

    if (bid < PB_CVT) {
        int n4 = T_TOKENS * D_DIM / 4;
        for (int j = bid * 256 + threadIdx.x; j < n4; j += PB_CVT * 256) {
            float4v v = ((const float4v*)x)[j];
            unsigned long long o =
                (unsigned long long)f2bf(v[0]) |
                ((unsigned long long)f2bf(v[1]) << 16) |
                ((unsigned long long)f2bf(v[2]) << 32) |
                ((unsigned long long)f2bf(v[3]) << 48);
            ((unsigned long long*)xb)[j] = o;
        }
        return;
    }
    bid -= PB_CVT;

    {   // zero out
        int n4 = T_TOKENS * D_DIM / 4;
        float4v z = {0.f, 0.f, 0.f, 0.f};
        for (int j = bid * 256 + threadIdx.x; j < n4; j += PB_ZERO * 256)
            ((float4v*)out)[j] = z;
    }
}

// ---------------------------------------------------------------- finalize
__global__ void k_finalize(const int* __restrict__ counts, int* __restrict__ pcount,
                           int* __restrict__ offs, int* __restrict__ nrb,
                           int* __restrict__ rbmap) {
    if (threadIdx.x == 0) {
        int acc = 0, rb = 0;
        for (int e = 0; e < E_NUM; ++e) {
            int pc = (counts[e] + BM - 1) / BM * BM;
            pcount[e] = pc;
            offs[e] = acc;
            for (int i = 0; i < pc / BM; ++i) rbmap[rb++] = e;
            acc += pc;
        }
        nrb[0] = rb;
    }
}

// ---------------------------------------------------------------- compact
__global__ void k_compact(const int* __restrict__ counts, const int* __restrict__ pcount,
                          const int* __restrict__ offs, const int* __restrict__ list,
                          const float* __restrict__ wtmp, int* __restrict__ clist,
                          float* __restrict__ cw) {
    int e = blockIdx.y;
    int s = blockIdx.x * 256 + threadIdx.x;
    if (s >= pcount[e]) return;
    int g = offs[e] + s;
    if (s < counts[e]) {
        clist[g] = list[e * T_TOKENS + s];
        cw[g] = wtmp[e * T_TOKENS + s];
    } else {
        clist[g] = 0;
        cw[g] = 0.f;
    }
}

// ------------------------------------------- up GEMM + w_down transpose (fused)
// blocks [0,1728): up GEMM (XCD-chunk swizzle, rb-inner)
// blocks [1728, 1728+4608): wdn transpose rides the idle memory pipe
__global__ void k_up_gemm(const ushort_t* __restrict__ xb, const ushort_t* __restrict__ wupT,
                          const float* __restrict__ b_up, const int* __restrict__ nrb,
                          const int* __restrict__ rbmap, const int* __restrict__ clist,
                          ushort_t* __restrict__ h,
                          const float* __restrict__ wdn, ushort_t* __restrict__ wdnT) {
    __shared__ __align__(16) char smem_raw[32768];

    if (blockIdx.x >= UP_BLOCKS) {
        float (*tile)[65] = reinterpret_cast<float(*)[65]>(smem_raw);
        transpose_tile64(wdn, wdnT, F_DIM, D_DIM, blockIdx.x - UP_BLOCKS, tile);
        return;
    }

    int wg = blockIdx.x;
    int lin = (wg & 7) * (NBU * RBMAX / 8) + (wg >> 3);
    int nb = lin / RBMAX;
    int rb = lin % RBMAX;
    if (rb >= nrb[0]) return;
    int e = rbmap[rb];
    ushort_t (*As)[BM][BK] = reinterpret_cast<ushort_t(*)[BM][BK]>(smem_raw);
    ushort_t (*Bs)[BM][BK] = reinterpret_cast<ushort_t(*)[BM][BK]>(smem_raw + 16384);
    int t = threadIdx.x, wave = t >> 6, lane = t & 63;
    int wm = wave >> 1, wn = wave & 1;

    int row0 = rb * BM;
    int tokA0 = clist[row0 + (t >> 2)];
    int tokA1 = clist[row0 + 64 + (t >> 2)];
    const ushort_t* wb = wupT + (size_t)e * F_DIM * D_DIM + (size_t)(nb * BN) * D_DIM;

    float4v acc[4][4];
#pragma unroll
    for (int i = 0; i < 4; ++i)
#pragma unroll
        for (int j = 0; j < 4; ++j)
#pragma unroll
            for (int q = 0; q < 4; ++q) acc[i][j][q] = 0.f;

    int csw = (((t & 3) ^ ((t >> 3) & 3))) * 8;    // staged src chunk (swizzled)
    int swoff = (((lane >> 4) ^ (((lane & 15) >> 1) & 3))) * 8;  // read-side

    const ushort_t* gA0 = xb + (size_t)tokA0 * D_DIM + csw;
    const ushort_t* gA1 = xb + (size_t)tokA1 * D_DIM + csw;
    const ushort_t* gB0 = wb + (size_t)(t >> 2) * D_DIM + csw;
    const ushort_t* gB1 = wb + (size_t)(64 + (t >> 2)) * D_DIM + csw;

#define STAGE_UP(buf, kt) do { int k0 = (kt) * BK;                            \
        char* AsB = (char*)&As[buf][0][0]; char* BsB = (char*)&Bs[buf][0][0]; \
        GLOAD_LDS16(gA0 + k0, AsB + wave * 1024);                             \
        GLOAD_LDS16(gA1 + k0, AsB + 4096 + wave * 1024);                      \
        GLOAD_LDS16(gB0 + k0, BsB + wave * 1024);                             \
        GLOAD_LDS16(gB1 + k0, BsB + 4096 + wave * 1024); } while (0)

    STAGE_UP(0, 0);
    __syncthreads();
    const int nt = D_DIM / BK;
    for (int kt = 0; kt < nt; ++kt) {
        int buf = kt & 1;
        if (kt + 1 < nt) STAGE_UP(buf ^ 1, kt + 1);
        short8 af[4], bfr[4];
#pragma unroll
        for (int m = 0; m < 4; ++m)
            af[m] = *(const short8*)&As[buf][wm * 64 + m * 16 + (lane & 15)][swoff];
#pragma unroll
        for (int n = 0; n < 4; ++n)
            bfr[n] = *(const short8*)&Bs[buf][wn * 64 + n * 16 + (lane & 15)][swoff];
#pragma unroll
        for (int m = 0; m < 4; ++m)
#pragma unroll
            for (int n = 0; n < 4; ++n)
                acc[m][n] = __builtin_amdgcn_mfma_f32_16x16x32_bf16(af[m], bfr[n], acc[m][n], 0, 0, 0);
        __syncthreads();
    }

#pragma unroll
    for (int m = 0; m < 4; ++m) {
        int row_local = wm * 64 + m * 16 + (lane >> 4) * 4;
#pragma unroll
        for (int n = 0; n < 4; ++n) {
            int col = nb * BN + wn * 64 + n * 16 + (lane & 15);
            float bia = b_up[e * F_DIM + col];
#pragma unroll
            for (int j = 0; j < 4; ++j) {
                float v = acc[m][n][j] + bia;
                h[(size_t)(row0 + row_local + j) * F_DIM + col] = f2bf(gelu_fast(v));
            }
        }
    }
}

// ---------------------------------------------------------------- down GEMM + combine
__global__ void k_down_gemm(const ushort_t* __restrict__ h, const ushort_t* __restrict__ wdT,
                            const float* __restrict__ b_down, const int* __restrict__ nrb,
                            const int* __restrict__ rbmap, const int* __restrict__ clist,
                            const float* __restrict__ cw, float* __restrict__ out) {
    int wg = blockIdx.x;
    int lin = (wg & 7) * (NBD * RBMAX * KS_DOWN / 8) + (wg >> 3);
    int nb = lin % NBD;
    int rest = lin / NBD;
    int rb = rest % RBMAX;
    int kc = rest / RBMAX;
    if (rb >= nrb[0]) return;
    int e = rbmap[rb];
    __shared__ __align__(16) ushort_t As[2][BM][BK];
    __shared__ __align__(16) ushort_t Bs[2][BN][BK];
    int t = threadIdx.x, wave = t >> 6, lane = t & 63;
    int wm = wave >> 1, wn = wave & 1;

    int row0 = rb * BM;
    int kbase = kc * KCH;
    const ushort_t* ha = h + (size_t)row0 * F_DIM + kbase;
    const ushort_t* wb = wdT + (size_t)e * D_DIM * F_DIM + (size_t)(nb * BN) * F_DIM + kbase;

    float4v acc[4][4];
#pragma unroll
    for (int i = 0; i < 4; ++i)
#pragma unroll
        for (int j = 0; j < 4; ++j)
#pragma unroll
            for (int q = 0; q < 4; ++q) acc[i][j][q] = 0.f;

    int csw = (((t & 3) ^ ((t >> 3) & 3))) * 8;
    int swoff = (((lane >> 4) ^ (((lane & 15) >> 1) & 3))) * 8;

    const ushort_t* gA0 = ha + (size_t)(t >> 2) * F_DIM + csw;
    const ushort_t* gA1 = ha + (size_t)(64 + (t >> 2)) * F_DIM + csw;
    const ushort_t* gB0 = wb + (size_t)(t >> 2) * F_DIM + csw;
    const ushort_t* gB1 = wb + (size_t)(64 + (t >> 2)) * F_DIM + csw;

#define STAGE_DN(buf, kt) do { int k0 = (kt) * BK;                       \
        char* AsB = (char*)&As[buf][0][0]; char* BsB = (char*)&Bs[buf][0][0]; \
        GLOAD_LDS16(gA0 + k0, AsB + wave * 1024);                        \
        GLOAD_LDS16(gA1 + k0, AsB + 4096 + wave * 1024);                 \
        GLOAD_LDS16(gB0 + k0, BsB + wave * 1024);                        \
        GLOAD_LDS16(gB1 + k0, BsB + 4096 + wave * 1024); } while (0)

    STAGE_DN(0, 0);
    __syncthreads();
    const int nt = KCH / BK;
    for (int kt = 0; kt < nt; ++kt) {
        int buf = kt & 1;
        if (kt + 1 < nt) STAGE_DN(buf ^ 1, kt + 1);
        short8 af[4], bfr[4];
#pragma unroll
        for (int m = 0; m < 4; ++m)
            af[m] = *(const short8*)&As[buf][wm * 64 + m * 16 + (lane & 15)][swoff];
#pragma unroll
        for (int n = 0; n < 4; ++n)
            bfr[n] = *(const short8*)&Bs[buf][wn * 64 + n * 16 + (lane & 15)][swoff];
#pragma unroll
        for (int m = 0; m < 4; ++m)
#pragma unroll
            for (int n = 0; n < 4; ++n)
                acc[m][n] = __builtin_amdgcn_mfma_f32_16x16x32_bf16(af[m], bfr[n], acc[m][n], 0, 0, 0);
        __syncthreads();
    }

#pragma unroll
    for (int m = 0; m < 4; ++m) {
        int row_local = wm * 64 + m * 16 + (lane >> 4) * 4;
#pragma unroll
        for (int j = 0; j < 4; ++j) {
            int rl = row0 + row_local + j;
            int tok = clist[rl];
            float w = cw[rl];
            if (w != 0.f) {
#pragma unroll
                for (int n = 0; n < 4; ++n) {
                    int col = nb * BN + wn * 64 + n * 16 + (lane & 15);
                    float v = acc[m][n][j];
                    if (kc == 0) v += b_down[e * D_DIM + col];
                    atomicAdd(&out[(size_t)tok * D_DIM + col], w * v);
                }
            }
        }
    }
}

// ---------------------------------------------------------------- launch
extern "C" void kernel_launch(void* const* d_in, const int* in_sizes, int n_in,
                              void* d_out, int out_size, void* d_ws, size_t ws_size,
                              hipStream_t stream) {
    const float* x   = (const float*)d_in[0];   // [2,2048,768]
    const float* gw  = (const float*)d_in[1];   // [768,8]
    const float* wup = (const float*)d_in[2];   // [8,768,3072]
    const float* bup = (const float*)d_in[3];   // [8,3072]
    const float* wdn = (const float*)d_in[4];   // [8,3072,768]
    const float* bdn = (const float*)d_in[5];   // [8,768]
    float* out = (float*)d_out;

    char* ws = (char*)d_ws;
    int*   counts = (int*)(ws);
    int*   pcount = (int*)(ws + 32);
    int*   offs   = (int*)(ws + 64);
    int*   nrb    = (int*)(ws + 96);
    int*   rbmap  = (int*)(ws + 128);
    int*   list   = (int*)(ws + 1024);
    float* wtmp   = (float*)(ws + 1024 + (size_t)E_NUM * T_TOKENS * 4);
    size_t p = 1024 + (size_t)E_NUM * T_TOKENS * 8;
    int*   clist  = (int*)(ws + p); p += (size_t)(RBMAX * BM) * 4;
    float* cwp    = (float*)(ws + p); p += (size_t)(RBMAX * BM) * 4;
    p = (p + 255) & ~(size_t)255;
    ushort_t* xb   = (ushort_t*)(ws + p); p += (size_t)T_TOKENS * D_DIM * 2;
    ushort_t* wupT = (ushort_t*)(ws + p); p += (size_t)E_NUM * D_DIM * F_DIM * 2;
    ushort_t* wdnT = (ushort_t*)(ws + p); p += (size_t)E_NUM * D_DIM * F_DIM * 2;
    ushort_t* hbuf = (ushort_t*)(ws + p); p += (size_t)(RBMAX * BM) * F_DIM * 2;

    hipMemsetAsync(counts, 0, E_NUM * sizeof(int), stream);
    k_prep1<<<P1_TOTAL, 256, 0, stream>>>(x, gw, wup, counts, list, wtmp,
                                          xb, wupT, out);
    k_finalize<<<1, 64, 0, stream>>>(counts, pcount, offs, nrb, rbmap);
    k_compact<<<dim3(T_TOKENS / 256, E_NUM), 256, 0, stream>>>(
        counts, pcount, offs, list, wtmp, clist, cwp);
    k_up_gemm<<<UP_BLOCKS + TB_WUP, 256, 0, stream>>>(
        xb, wupT, bup, nrb, rbmap, clist, hbuf, wdn, wdnT);
    k_down_gemm<<<NBD * RBMAX * KS_DOWN, 256, 0, stream>>>(
        hbuf, wdnT, bdn, nrb, rbmap, clist, cwp, out);
}

// Round 5
// 309.134 us; speedup vs baseline: 1.1401x; 1.1288x over previous
//
#include <hip/hip_runtime.h>
#include <hip/hip_bf16.h>
#include <math.h>

// Problem constants (B=2,S=2048 -> T=4096 tokens)
#define T_TOKENS 4096
#define D_DIM 768
#define F_DIM 3072
#define E_NUM 8

#define BM 128
#define BN 128
#define BK 32
#define RBMAX 72          // max padded 128-row blocks: (8192 + 8*127)/128 <= 72
#define NBU (F_DIM / BN)        // 24
#define NBD (D_DIM / BN)        // 6
#define UP_BLOCKS (NBU * RBMAX) // 1728
#define DBM 64                  // down-GEMM row-tile
#define DN_BLOCKS (NBD * RBMAX * 2)  // 864

typedef __attribute__((ext_vector_type(8))) short short8;
typedef __attribute__((ext_vector_type(4))) short short4v;
typedef __attribute__((ext_vector_type(4))) float float4v;
typedef unsigned short ushort_t;

__device__ __forceinline__ ushort_t f2bf(float f) {
    union { float f; unsigned u; } v; v.f = f;
    unsigned r = v.u + 0x7fffu + ((v.u >> 16) & 1u);   // RNE
    return (ushort_t)(r >> 16);
}

__device__ __forceinline__ float gelu_fast(float v) {
    float u = v + 0.044715f * v * v * v;
    return v / (1.f + __expf(-1.5957691216f * u));
}

#define GLOAD_LDS16(gp, lp) __builtin_amdgcn_global_load_lds( \
    (const __attribute__((address_space(1))) void*)(gp),      \
    (__attribute__((address_space(3))) void*)(lp), 16, 0, 0)

// ------------------------------------------------- vectorized transpose tile
// one 64x64 tile: in [E][R][C] fp32 -> out [E][C][R] bf16
__device__ __forceinline__ void transpose_tile64(const float* __restrict__ in,
                                                 ushort_t* __restrict__ outp,
                                                 int R, int C, int lb,
                                                 float (*tile)[65]) {
    int tpr = C / 64, tpc = R / 64;
    int e = lb / (tpr * tpc);
    int rem = lb % (tpr * tpc);
    int r0 = (rem / tpr) * 64, c0 = (rem % tpr) * 64;
    const float* ip = in + (size_t)e * R * C;
    ushort_t* opp = outp + (size_t)e * R * C;
    int tr = threadIdx.x >> 4;           // 0..15
    int tc = (threadIdx.x & 15) * 4;     // 0,4,...,60
#pragma unroll
    for (int i = 0; i < 4; ++i) {
        int r = tr + i * 16;
        *(float4v*)&tile[r][tc] = *(const float4v*)&ip[(size_t)(r0 + r) * C + c0 + tc];
    }
    __syncthreads();
#pragma unroll
    for (int i = 0; i < 4; ++i) {
        int rr = tr + i * 16;            // output row (= original col c0+rr)
        short4v sv;
#pragma unroll
        for (int k = 0; k < 4; ++k) sv[k] = (short)f2bf(tile[tc + k][rr]);
        *(short4v*)&opp[(size_t)(c0 + rr) * R + r0 + tc] = sv;
    }
}

// ============================================================ prep phase 1
#define TB_WUP 4608
#define TB_WDN 4608
#define PB_GATE 1024
#define PB_CVT 1024
#define P1_TOTAL (TB_WUP + TB_WDN + PB_GATE + PB_CVT)

__global__ void k_prep1(const float* __restrict__ x, const float* __restrict__ gw,
                        const float* __restrict__ wup, const float* __restrict__ wdn,
                        int* __restrict__ counts, int* __restrict__ list,
                        float* __restrict__ wsel, ushort_t* __restrict__ xb,
                        ushort_t* __restrict__ wupT, ushort_t* __restrict__ wdnT) {
    __shared__ float tile[64][65];
    int bid = blockIdx.x;

    if (bid < TB_WUP) {
        transpose_tile64(wup, wupT, D_DIM, F_DIM, bid, tile);
        return;
    }
    bid -= TB_WUP;
    if (bid < TB_WDN) {
        transpose_tile64(wdn, wdnT, F_DIM, D_DIM, bid, tile);
        return;
    }
    bid -= TB_WDN;

    if (bid < PB_GATE) {
        int wave = threadIdx.x >> 6, lane = threadIdx.x & 63;
        int t = bid * 4 + wave;
        float acc[E_NUM];
#pragma unroll
        for (int e = 0; e < E_NUM; ++e) acc[e] = 0.f;
        const float* xr = x + (size_t)t * D_DIM;
        for (int d = lane; d < D_DIM; d += 64) {
            float xv = xr[d];
            const float* g = gw + d * E_NUM;
#pragma unroll
            for (int e = 0; e < E_NUM; ++e) acc[e] += xv * g[e];
        }
#pragma unroll
        for (int e = 0; e < E_NUM; ++e) {
#pragma unroll
            for (int s = 32; s >= 1; s >>= 1) acc[e] += __shfl_xor(acc[e], s);
        }
        if (lane == 0) {
            float mx = acc[0];
#pragma unroll
            for (int e = 1; e < E_NUM; ++e) mx = fmaxf(mx, acc[e]);
            float p[E_NUM], sum = 0.f;
#pragma unroll
            for (int e = 0; e < E_NUM; ++e) { p[e] = expf(acc[e] - mx); sum += p[e]; }
            float inv = 1.f / sum;
#pragma unroll
            for (int e = 0; e < E_NUM; ++e) p[e] *= inv;
            int e1 = 0;
#pragma unroll
            for (int e = 1; e < E_NUM; ++e) if (p[e] > p[e1]) e1 = e;
            int e2 = (e1 == 0) ? 1 : 0;
#pragma unroll
            for (int e = 0; e < E_NUM; ++e) if (e != e1 && p[e] > p[e2]) e2 = e;
            int s1 = atomicAdd(&counts[e1], 1);
            list[e1 * T_TOKENS + s1] = t * 2 + 0;      // token | slot bit
            int s2 = atomicAdd(&counts[e2], 1);
            list[e2 * T_TOKENS + s2] = t * 2 + 1;
            wsel[t * 2 + 0] = p[e1];
            wsel[t * 2 + 1] = p[e2];
        }
        return;
    }
    bid -= PB_GATE;

    {   // x -> bf16
        int n4 = T_TOKENS * D_DIM / 4;
        for (int j = bid * 256 + threadIdx.x; j < n4; j += PB_CVT * 256) {
            float4v v = ((const float4v*)x)[j];
            unsigned long long o =
                (unsigned long long)f2bf(v[0]) |
                ((unsigned long long)f2bf(v[1]) << 16) |
                ((unsigned long long)f2bf(v[2]) << 32) |
                ((unsigned long long)f2bf(v[3]) << 48);
            ((unsigned long long*)xb)[j] = o;
        }
    }
}

// ---------------------------------------------------------------- finalize
__global__ void k_finalize(const int* __restrict__ counts, int* __restrict__ pcount,
                           int* __restrict__ offs, int* __restrict__ nrb,
                           int* __restrict__ rbmap) {
    if (threadIdx.x == 0) {
        int acc = 0, rb = 0;
        for (int e = 0; e < E_NUM; ++e) {
            int pc = (counts[e] + BM - 1) / BM * BM;
            pcount[e] = pc;
            offs[e] = acc;
            for (int i = 0; i < pc / BM; ++i) rbmap[rb++] = e;
            acc += pc;
        }
        nrb[0] = rb;
    }
}

// ---------------------------------------------------------------- compact
// per-expert lists -> global padded rows; also token->row reverse map
__global__ void k_compact(const int* __restrict__ counts, const int* __restrict__ pcount,
                          const int* __restrict__ offs, const int* __restrict__ list,
                          int* __restrict__ clist, int* __restrict__ rowOf) {
    int e = blockIdx.y;
    int s = blockIdx.x * 256 + threadIdx.x;
    if (s >= pcount[e]) return;
    int g = offs[e] + s;
    if (s < counts[e]) {
        int v = list[e * T_TOKENS + s];
        clist[g] = v >> 1;
        rowOf[v] = g;                 // v = tok*2 + slot
    } else {
        clist[g] = 0;                 // padding row gathers token 0 (output unused)
    }
}

// ---------------------------------------------------------------- up GEMM
// flat grid, XCD-chunk swizzle, rb-inner
__global__ void k_up_gemm(const ushort_t* __restrict__ xb, const ushort_t* __restrict__ wupT,
                          const float* __restrict__ b_up, const int* __restrict__ nrb,
                          const int* __restrict__ rbmap, const int* __restrict__ clist,
                          ushort_t* __restrict__ h) {
    int wg = blockIdx.x;
    int lin = (wg & 7) * (UP_BLOCKS / 8) + (wg >> 3);
    int nb = lin / RBMAX;
    int rb = lin % RBMAX;
    if (rb >= nrb[0]) return;
    int e = rbmap[rb];
    __shared__ __align__(16) ushort_t As[2][BM][BK];
    __shared__ __align__(16) ushort_t Bs[2][BN][BK];
    int t = threadIdx.x, wave = t >> 6, lane = t & 63;
    int wm = wave >> 1, wn = wave & 1;

    int row0 = rb * BM;
    int tokA0 = clist[row0 + (t >> 2)];
    int tokA1 = clist[row0 + 64 + (t >> 2)];
    const ushort_t* wb = wupT + (size_t)e * F_DIM * D_DIM + (size_t)(nb * BN) * D_DIM;

    float4v acc[4][4];
#pragma unroll
    for (int i = 0; i < 4; ++i)
#pragma unroll
        for (int j = 0; j < 4; ++j)
#pragma unroll
            for (int q = 0; q < 4; ++q) acc[i][j][q] = 0.f;

    int csw = (((t & 3) ^ ((t >> 3) & 3))) * 8;    // staged src chunk (swizzled)
    int swoff = (((lane >> 4) ^ (((lane & 15) >> 1) & 3))) * 8;  // read-side

    const ushort_t* gA0 = xb + (size_t)tokA0 * D_DIM + csw;
    const ushort_t* gA1 = xb + (size_t)tokA1 * D_DIM + csw;
    const ushort_t* gB0 = wb + (size_t)(t >> 2) * D_DIM + csw;
    const ushort_t* gB1 = wb + (size_t)(64 + (t >> 2)) * D_DIM + csw;

#define STAGE_UP(buf, kt) do { int k0 = (kt) * BK;                            \
        char* AsB = (char*)&As[buf][0][0]; char* BsB = (char*)&Bs[buf][0][0]; \
        GLOAD_LDS16(gA0 + k0, AsB + wave * 1024);                             \
        GLOAD_LDS16(gA1 + k0, AsB + 4096 + wave * 1024);                      \
        GLOAD_LDS16(gB0 + k0, BsB + wave * 1024);                             \
        GLOAD_LDS16(gB1 + k0, BsB + 4096 + wave * 1024); } while (0)

    STAGE_UP(0, 0);
    __syncthreads();
    const int nt = D_DIM / BK;
    for (int kt = 0; kt < nt; ++kt) {
        int buf = kt & 1;
        if (kt + 1 < nt) STAGE_UP(buf ^ 1, kt + 1);
        short8 af[4], bfr[4];
#pragma unroll
        for (int m = 0; m < 4; ++m)
            af[m] = *(const short8*)&As[buf][wm * 64 + m * 16 + (lane & 15)][swoff];
#pragma unroll
        for (int n = 0; n < 4; ++n)
            bfr[n] = *(const short8*)&Bs[buf][wn * 64 + n * 16 + (lane & 15)][swoff];
#pragma unroll
        for (int m = 0; m < 4; ++m)
#pragma unroll
            for (int n = 0; n < 4; ++n)
                acc[m][n] = __builtin_amdgcn_mfma_f32_16x16x32_bf16(af[m], bfr[n], acc[m][n], 0, 0, 0);
        __syncthreads();
    }

#pragma unroll
    for (int m = 0; m < 4; ++m) {
        int row_local = wm * 64 + m * 16 + (lane >> 4) * 4;
#pragma unroll
        for (int n = 0; n < 4; ++n) {
            int col = nb * BN + wn * 64 + n * 16 + (lane & 15);
            float bia = b_up[e * F_DIM + col];
#pragma unroll
            for (int j = 0; j < 4; ++j) {
                float v = acc[m][n][j] + bia;
                h[(size_t)(row0 + row_local + j) * F_DIM + col] = f2bf(gelu_fast(v));
            }
        }
    }
}

// ---------------------------------------------------------------- down GEMM
// 64x128 tile, plain fp32 stores into ybuf (bias folded), no atomics
__global__ void k_down_gemm(const ushort_t* __restrict__ h, const ushort_t* __restrict__ wdT,
                            const float* __restrict__ b_down, const int* __restrict__ nrb,
                            const int* __restrict__ rbmap, float* __restrict__ yb) {
    int wg = blockIdx.x;
    int lin = (wg & 7) * (DN_BLOCKS / 8) + (wg >> 3);
    int nb = lin / (RBMAX * 2);
    int rbD = lin % (RBMAX * 2);
    if ((rbD >> 1) >= nrb[0]) return;
    int e = rbmap[rbD >> 1];
    __shared__ __align__(16) ushort_t As[2][DBM][BK];
    __shared__ __align__(16) ushort_t Bs[2][BN][BK];
    int t = threadIdx.x, wave = t >> 6, lane = t & 63;
    int wm = wave >> 1, wn = wave & 1;

    int row0 = rbD * DBM;
    const ushort_t* ha = h + (size_t)row0 * F_DIM;
    const ushort_t* wb = wdT + (size_t)e * D_DIM * F_DIM + (size_t)(nb * BN) * F_DIM;

    float4v acc[2][4];
#pragma unroll
    for (int i = 0; i < 2; ++i)
#pragma unroll
        for (int j = 0; j < 4; ++j)
#pragma unroll
            for (int q = 0; q < 4; ++q) acc[i][j][q] = 0.f;

    int csw = (((t & 3) ^ ((t >> 3) & 3))) * 8;
    int swoff = (((lane >> 4) ^ (((lane & 15) >> 1) & 3))) * 8;

    const ushort_t* gA0 = ha + (size_t)(t >> 2) * F_DIM + csw;
    const ushort_t* gB0 = wb + (size_t)(t >> 2) * F_DIM + csw;
    const ushort_t* gB1 = wb + (size_t)(64 + (t >> 2)) * F_DIM + csw;

#define STAGE_DN(buf, kt) do { int k0 = (kt) * BK;                            \
        char* AsB = (char*)&As[buf][0][0]; char* BsB = (char*)&Bs[buf][0][0]; \
        GLOAD_LDS16(gA0 + k0, AsB + wave * 1024);                             \
        GLOAD_LDS16(gB0 + k0, BsB + wave * 1024);                             \
        GLOAD_LDS16(gB1 + k0, BsB + 4096 + wave * 1024); } while (0)

    STAGE_DN(0, 0);
    __syncthreads();
    const int nt = F_DIM / BK;
    for (int kt = 0; kt < nt; ++kt) {
        int buf = kt & 1;
        if (kt + 1 < nt) STAGE_DN(buf ^ 1, kt + 1);
        short8 af[2], bfr[4];
#pragma unroll
        for (int m = 0; m < 2; ++m)
            af[m] = *(const short8*)&As[buf][wm * 32 + m * 16 + (lane & 15)][swoff];
#pragma unroll
        for (int n = 0; n < 4; ++n)
            bfr[n] = *(const short8*)&Bs[buf][wn * 64 + n * 16 + (lane & 15)][swoff];
#pragma unroll
        for (int m = 0; m < 2; ++m)
#pragma unroll
            for (int n = 0; n < 4; ++n)
                acc[m][n] = __builtin_amdgcn_mfma_f32_16x16x32_bf16(af[m], bfr[n], acc[m][n], 0, 0, 0);
        __syncthreads();
    }

#pragma unroll
    for (int m = 0; m < 2; ++m) {
        int row_local = wm * 32 + m * 16 + (lane >> 4) * 4;
#pragma unroll
        for (int n = 0; n < 4; ++n) {
            int col = nb * BN + wn * 64 + n * 16 + (lane & 15);
            float bia = b_down[e * D_DIM + col];
#pragma unroll
            for (int j = 0; j < 4; ++j) {
                yb[(size_t)(row0 + row_local + j) * D_DIM + col] = acc[m][n][j] + bia;
            }
        }
    }
}

// ---------------------------------------------------------------- combine
// out[t] = w0 * yb[g0] + w1 * yb[g1]
__global__ void k_combine(const float* __restrict__ yb, const int* __restrict__ rowOf,
                          const float* __restrict__ wsel, float* __restrict__ out) {
    int wave = threadIdx.x >> 6, lane = threadIdx.x & 63;
    int t = blockIdx.x * 4 + wave;
    int g0 = rowOf[t * 2], g1 = rowOf[t * 2 + 1];
    float w0 = wsel[t * 2], w1 = wsel[t * 2 + 1];
    const float4v* y0 = (const float4v*)(yb + (size_t)g0 * D_DIM);
    const float4v* y1 = (const float4v*)(yb + (size_t)g1 * D_DIM);
    float4v* o = (float4v*)(out + (size_t)t * D_DIM);
#pragma unroll
    for (int i = 0; i < 3; ++i) {
        int idx = lane + i * 64;
        float4v a = y0[idx], b = y1[idx];
        float4v r;
#pragma unroll
        for (int q = 0; q < 4; ++q) r[q] = w0 * a[q] + w1 * b[q];
        o[idx] = r;
    }
}

// ---------------------------------------------------------------- launch
extern "C" void kernel_launch(void* const* d_in, const int* in_sizes, int n_in,
                              void* d_out, int out_size, void* d_ws, size_t ws_size,
                              hipStream_t stream) {
    const float* x   = (const float*)d_in[0];   // [2,2048,768]
    const float* gw  = (const float*)d_in[1];   // [768,8]
    const float* wup = (const float*)d_in[2];   // [8,768,3072]
    const float* bup = (const float*)d_in[3];   // [8,3072]
    const float* wdn = (const float*)d_in[4];   // [8,3072,768]
    const float* bdn = (const float*)d_in[5];   // [8,768]
    float* out = (float*)d_out;

    char* ws = (char*)d_ws;
    int*   counts = (int*)(ws);
    int*   pcount = (int*)(ws + 32);
    int*   offs   = (int*)(ws + 64);
    int*   nrb    = (int*)(ws + 96);
    int*   rbmap  = (int*)(ws + 128);
    int*   list   = (int*)(ws + 1024);
    size_t p = 1024 + (size_t)E_NUM * T_TOKENS * 4;
    int*   clist  = (int*)(ws + p); p += (size_t)(RBMAX * BM) * 4;
    int*   rowOf  = (int*)(ws + p); p += (size_t)T_TOKENS * 2 * 4;
    float* wsel   = (float*)(ws + p); p += (size_t)T_TOKENS * 2 * 4;
    p = (p + 255) & ~(size_t)255;
    size_t p_xb = p;
    ushort_t* xb   = (ushort_t*)(ws + p); p += (size_t)T_TOKENS * D_DIM * 2;
    ushort_t* wupT = (ushort_t*)(ws + p); p += (size_t)E_NUM * D_DIM * F_DIM * 2;
    ushort_t* wdnT = (ushort_t*)(ws + p); p += (size_t)E_NUM * D_DIM * F_DIM * 2;
    ushort_t* hbuf = (ushort_t*)(ws + p); p += (size_t)(RBMAX * BM) * F_DIM * 2;
    // ybuf aliases xb+wupT (both dead once down GEMM runs): 28.3MB <= 43.5MB
    float* ybuf = (float*)(ws + p_xb);

    hipMemsetAsync(counts, 0, E_NUM * sizeof(int), stream);
    k_prep1<<<P1_TOTAL, 256, 0, stream>>>(x, gw, wup, wdn, counts, list, wsel,
                                          xb, wupT, wdnT);
    k_finalize<<<1, 64, 0, stream>>>(counts, pcount, offs, nrb, rbmap);
    k_compact<<<dim3(T_TOKENS / 256, E_NUM), 256, 0, stream>>>(
        counts, pcount, offs, list, clist, rowOf);
    k_up_gemm<<<UP_BLOCKS, 256, 0, stream>>>(
        xb, wupT, bup, nrb, rbmap, clist, hbuf);
    k_down_gemm<<<DN_BLOCKS, 256, 0, stream>>>(
        hbuf, wdnT, bdn, nrb, rbmap, ybuf);
    k_combine<<<T_TOKENS / 4, 256, 0, stream>>>(ybuf, rowOf, wsel, out);
}